// Round 1
// 1566.771 us; speedup vs baseline: 1.0874x; 1.0874x over previous
//
#include <hip/hip_runtime.h>
#include <hip/hip_bf16.h>

// Problem dims
constexpr int NV   = 10000;  // vocab
constexpr int NE   = 512;    // embed
constexpr int NENC = 2048;   // encoder dim
constexpr int ND   = 512;    // decoder dim
constexpr int NA   = 512;    // attention dim
constexpr int NB   = 64;     // batch
constexpr int NL   = 49;     // locations
constexpr int NT   = 20;     // steps
constexpr int KX   = NE + NENC + ND;  // 3072 : x = [emb | context | h]
constexpr int KIH  = NE + NENC;       // 2560 : W_ih inner dim

typedef short bfrag __attribute__((ext_vector_type(8)));   // 8 bf16 (4 VGPRs)
typedef float f32x4 __attribute__((ext_vector_type(4)));   // MFMA acc

__device__ __forceinline__ float us2f(unsigned short u) {
    union { unsigned int i; float f; } x; x.i = (unsigned int)u << 16; return x.f;
}
__device__ __forceinline__ unsigned short f2us(float f) {  // RNE f32->bf16
    union { float f_; unsigned int u; } x; x.f_ = f;
    unsigned int r = (x.u + 0x7fffu + ((x.u >> 16) & 1u)) >> 16;
    return (unsigned short)r;
}

// ---------------------------------------------------------------------------
// K_mean: mean over L -> bf16. grid (B, NENC/256). Coalesced.
// ---------------------------------------------------------------------------
__launch_bounds__(256)
__global__ void k_mean(const float* __restrict__ enc, unsigned short* __restrict__ meanbf)
{
    const int b = blockIdx.x;
    const int e = blockIdx.y * 256 + threadIdx.x;
    const float* p = enc + (size_t)b * NL * NENC + e;
    float s = 0.f;
    #pragma unroll 7
    for (int l = 0; l < NL; ++l) s += p[(size_t)l * NENC];
    meanbf[(size_t)b * NENC + e] = f2us(s * (1.0f / NL));
}

// ---------------------------------------------------------------------------
// K_init_mfma: [h|c](64,1024) = meanbf(64,2048) @ WicT(1024,2048)^T + bias.
// n<512 -> h (bf16), n>=512 -> c (f32). grid 64 blocks x 4 waves (m-tiles).
// Replaces the old 16-block f32 k_init_gemm (latency-bound, 172 us).
// ---------------------------------------------------------------------------
__launch_bounds__(256)
__global__ void k_init_mfma(const unsigned short* __restrict__ meanbf,  // (64,2048)
                            const unsigned short* __restrict__ WicT,    // (1024,2048)
                            const float* __restrict__ bh, const float* __restrict__ bc,
                            unsigned short* __restrict__ hbf, float* __restrict__ c)
{
    const int wave = threadIdx.x >> 6, lane = threadIdx.x & 63;
    const int m0 = wave * 16, n0 = blockIdx.x * 16;   // 64*16 = 1024 cols
    const int r = lane & 15, quad = lane >> 4;
    const unsigned short* ap = meanbf + (size_t)(m0 + r) * NENC + quad * 8;
    const unsigned short* bp = WicT   + (size_t)(n0 + r) * NENC + quad * 8;
    f32x4 acc = {0.f, 0.f, 0.f, 0.f};
    #pragma unroll 8
    for (int k = 0; k < NENC; k += 32) {
        bfrag a = *(const bfrag*)(ap + k);
        bfrag b = *(const bfrag*)(bp + k);
        acc = __builtin_amdgcn_mfma_f32_16x16x32_bf16(a, b, acc, 0, 0, 0);
    }
    const int n = n0 + r;
    const bool isC = n >= ND;
    const float bv = isC ? bc[n - ND] : bh[n];
    #pragma unroll
    for (int i = 0; i < 4; ++i) {
        int m = m0 + quad * 4 + i;
        float v = acc[i] + bv;
        if (isC) c[(size_t)m * ND + (n - ND)] = v;
        else     hbf[(size_t)m * ND + n] = f2us(v);
    }
}

// ---------------------------------------------------------------------------
// K_cvt: f32 -> bf16 flat copy (n multiple of 4).
// ---------------------------------------------------------------------------
__launch_bounds__(256)
__global__ void k_cvt(const float* __restrict__ src, unsigned short* __restrict__ dst, int n)
{
    int i = (blockIdx.x * 256 + threadIdx.x) * 4;
    if (i < n) {
        float4 v = *(const float4*)(src + i);
        dst[i + 0] = f2us(v.x); dst[i + 1] = f2us(v.y);
        dst[i + 2] = f2us(v.z); dst[i + 3] = f2us(v.w);
    }
}

// ---------------------------------------------------------------------------
// K_transpose: (K,N) f32 -> (N,K) bf16.  grid (ceil(N/32), K/32), 256 thr.
// ---------------------------------------------------------------------------
__launch_bounds__(256)
__global__ void k_transpose(const float* __restrict__ src, unsigned short* __restrict__ dst,
                            int K, int N)
{
    __shared__ float t[32][33];
    const int nb = blockIdx.x * 32, kb = blockIdx.y * 32;
    const int tx = threadIdx.x & 31, ty = threadIdx.x >> 5;  // ty 0..7
    #pragma unroll
    for (int i = ty; i < 32; i += 8) {
        int n = nb + tx;
        t[i][tx] = (n < N) ? src[(size_t)(kb + i) * N + n] : 0.f;
    }
    __syncthreads();
    #pragma unroll
    for (int i = ty; i < 32; i += 8) {
        int n = nb + i;
        if (n < N) dst[(size_t)n * K + kb + tx] = f2us(t[tx][i]);
    }
}

// ---------------------------------------------------------------------------
// K_encproj_mfma: epb(3136,512)bf16 = encb(3136,2048) @ WeaT(512,2048)^T + bias
// wave = one 16x16 tile; block = 4 m-tiles of one n-tile. grid 49*32=1568.
// ---------------------------------------------------------------------------
__launch_bounds__(256)
__global__ void k_encproj_mfma(const unsigned short* __restrict__ encb,
                               const unsigned short* __restrict__ WeaT,
                               const float* __restrict__ bias,
                               unsigned short* __restrict__ epb)
{
    const int wave = threadIdx.x >> 6, lane = threadIdx.x & 63;
    const int ntile = blockIdx.x & 31;
    const int mg    = blockIdx.x >> 5;             // 0..48
    const int m0 = (mg * 4 + wave) * 16;
    const int n0 = ntile * 16;
    const int r = lane & 15, quad = lane >> 4;
    const unsigned short* ap = encb + (size_t)(m0 + r) * NENC + quad * 8;
    const unsigned short* bp = WeaT + (size_t)(n0 + r) * NENC + quad * 8;
    f32x4 acc = {0.f, 0.f, 0.f, 0.f};
    #pragma unroll 8
    for (int k = 0; k < NENC; k += 32) {
        bfrag a = *(const bfrag*)(ap + k);
        bfrag b = *(const bfrag*)(bp + k);
        acc = __builtin_amdgcn_mfma_f32_16x16x32_bf16(a, b, acc, 0, 0, 0);
    }
    const float bv = bias[n0 + r];
    #pragma unroll
    for (int i = 0; i < 4; ++i) {
        int m = m0 + quad * 4 + i;
        epb[(size_t)m * NA + n0 + r] = f2us(acc[i] + bv);
    }
}

// ---------------------------------------------------------------------------
// K_decproj_mfma: dp(64,512)f32 = hbf(64,512) @ WdaT(512,512)^T + bda. grid 32.
// ---------------------------------------------------------------------------
__launch_bounds__(256)
__global__ void k_decproj_mfma(const unsigned short* __restrict__ hbf,
                               const unsigned short* __restrict__ WdaT,
                               const float* __restrict__ bda,
                               float* __restrict__ dp)
{
    const int wave = threadIdx.x >> 6, lane = threadIdx.x & 63;
    const int m0 = wave * 16, n0 = blockIdx.x * 16;
    const int r = lane & 15, quad = lane >> 4;
    const unsigned short* ap = hbf + (size_t)(m0 + r) * ND + quad * 8;
    const unsigned short* bp = WdaT + (size_t)(n0 + r) * ND + quad * 8;
    f32x4 acc = {0.f, 0.f, 0.f, 0.f};
    #pragma unroll
    for (int k = 0; k < ND; k += 32) {
        bfrag a = *(const bfrag*)(ap + k);
        bfrag b = *(const bfrag*)(bp + k);
        acc = __builtin_amdgcn_mfma_f32_16x16x32_bf16(a, b, acc, 0, 0, 0);
    }
    const float bv = bda[n0 + r];
    #pragma unroll
    for (int i = 0; i < 4; ++i) {
        int m = m0 + quad * 4 + i;
        dp[(size_t)m * NA + n0 + r] = acc[i] + bv;
    }
}

// ---------------------------------------------------------------------------
// K_att: one block per b. scores=relu(ep+dp)@wf+b -> softmax -> alpha (f32 out)
// context from encb (bf16) -> x (bf16). Also x=[emb|context|h].
// ---------------------------------------------------------------------------
__launch_bounds__(256)
__global__ void k_att(int t,
                      const unsigned short* __restrict__ hbf,   // (B,D) bf16
                      const float* __restrict__ dpg,            // (B,A) f32
                      const unsigned short* __restrict__ epb,   // (B,L,A) bf16
                      const unsigned short* __restrict__ encb,  // (B,L,ENC) bf16
                      const float* __restrict__ wf,             // (A)
                      const float* __restrict__ bfs,            // scalar
                      const float* __restrict__ embt,           // (V,E) f32
                      const int* __restrict__ captions,         // (B,T)
                      unsigned short* __restrict__ x,           // (B,KX) bf16
                      float* __restrict__ alpha_out)            // (B,T,L) f32
{
    __shared__ float dp[NA];
    __shared__ float al[64];
    const int b = blockIdx.x, tid = threadIdx.x;

    for (int d = tid; d < ND; d += 256)
        x[(size_t)b * KX + NE + NENC + d] = hbf[(size_t)b * ND + d];  // h tail
    for (int a = tid; a < NA; a += 256)
        dp[a] = dpg[(size_t)b * NA + a];
    const int tok = captions[b * NT + t];
    for (int j = tid; j < NE; j += 256)
        x[(size_t)b * KX + j] = f2us(embt[(size_t)tok * NE + j]);
    __syncthreads();

    // scores: one wave per l
    const int wave = tid >> 6, lane = tid & 63;
    const float bfull = bfs[0];
    for (int l = wave; l < NL; l += 4) {
        const unsigned short* ep = epb + ((size_t)b * NL + l) * NA;
        float s = 0.f;
        #pragma unroll
        for (int a = lane; a < NA; a += 64) {
            float v = us2f(ep[a]) + dp[a];
            v = v > 0.f ? v : 0.f;
            s = fmaf(v, wf[a], s);
        }
        #pragma unroll
        for (int off = 32; off > 0; off >>= 1) s += __shfl_down(s, off, 64);
        if (lane == 0) al[l] = s + bfull;
    }
    __syncthreads();

    // softmax over L=49 (first wave)
    if (tid < 64) {
        float v = (tid < NL) ? al[tid] : -1e30f;
        float m = v;
        #pragma unroll
        for (int off = 32; off > 0; off >>= 1) m = fmaxf(m, __shfl_xor(m, off, 64));
        float e = (tid < NL) ? expf(v - m) : 0.f;
        float s = e;
        #pragma unroll
        for (int off = 32; off > 0; off >>= 1) s += __shfl_xor(s, off, 64);
        float a = e / s;
        if (tid < NL) {
            al[tid] = a;
            alpha_out[((size_t)b * NT + t) * NL + tid] = a;
        }
    }
    __syncthreads();

    // context -> x middle, bf16. thread covers 4 consecutive e, two passes.
    #pragma unroll
    for (int part = 0; part < 2; ++part) {
        const int e = part * 1024 + tid * 4;
        const unsigned short* p = encb + (size_t)b * NL * NENC + e;
        float s0 = 0.f, s1 = 0.f, s2 = 0.f, s3 = 0.f;
        #pragma unroll 7
        for (int l = 0; l < NL; ++l) {
            ushort4 v = *(const ushort4*)(p + (size_t)l * NENC);
            float a = al[l];
            s0 = fmaf(a, us2f(v.x), s0);
            s1 = fmaf(a, us2f(v.y), s1);
            s2 = fmaf(a, us2f(v.z), s2);
            s3 = fmaf(a, us2f(v.w), s3);
        }
        unsigned short* xo = x + (size_t)b * KX + NE + e;
        xo[0] = f2us(s0); xo[1] = f2us(s1); xo[2] = f2us(s2); xo[3] = f2us(s3);
    }
}

// ---------------------------------------------------------------------------
// K_gates_mfma: gates(64,2048)f32 = x(64,3072) @ [Wihb|Whhb]^T. grid 128.
// ---------------------------------------------------------------------------
__launch_bounds__(256)
__global__ void k_gates_mfma(const unsigned short* __restrict__ x,     // (64,3072)
                             const unsigned short* __restrict__ Wihb,  // (2048,2560)
                             const unsigned short* __restrict__ Whhb,  // (2048,512)
                             float* __restrict__ gates)                // (64,2048)
{
    const int wave = threadIdx.x >> 6, lane = threadIdx.x & 63;
    const int m0 = wave * 16, n0 = blockIdx.x * 16;
    const int r = lane & 15, quad = lane >> 4;
    const unsigned short* ap  = x + (size_t)(m0 + r) * KX + quad * 8;
    const unsigned short* bp1 = Wihb + (size_t)(n0 + r) * KIH + quad * 8;
    const unsigned short* bp2 = Whhb + (size_t)(n0 + r) * ND + quad * 8;
    f32x4 acc = {0.f, 0.f, 0.f, 0.f};
    #pragma unroll 8
    for (int k = 0; k < KIH; k += 32) {
        bfrag a = *(const bfrag*)(ap + k);
        bfrag b = *(const bfrag*)(bp1 + k);
        acc = __builtin_amdgcn_mfma_f32_16x16x32_bf16(a, b, acc, 0, 0, 0);
    }
    #pragma unroll
    for (int k = 0; k < ND; k += 32) {
        bfrag a = *(const bfrag*)(ap + KIH + k);
        bfrag b = *(const bfrag*)(bp2 + k);
        acc = __builtin_amdgcn_mfma_f32_16x16x32_bf16(a, b, acc, 0, 0, 0);
    }
    #pragma unroll
    for (int i = 0; i < 4; ++i) {
        int m = m0 + quad * 4 + i;
        gates[(size_t)m * (4 * ND) + n0 + r] = acc[i];
    }
}

// ---------------------------------------------------------------------------
// K_lstm: gates + biases -> i,f,g,o -> c (f32), h (bf16). grid 128.
// ---------------------------------------------------------------------------
__launch_bounds__(256)
__global__ void k_lstm(const float* __restrict__ gates,  // (B,2048)
                       const float* __restrict__ bih, const float* __restrict__ bhh,
                       unsigned short* __restrict__ hbf, float* __restrict__ c)
{
    const int idx = blockIdx.x * 256 + threadIdx.x;  // 0..32767
    const int b = idx >> 9, d = idx & 511;
    const float* gp = gates + (size_t)b * (4 * ND);
    float gi = gp[d]        + bih[d]        + bhh[d];
    float gf = gp[d + 512]  + bih[d + 512]  + bhh[d + 512];
    float gg = gp[d + 1024] + bih[d + 1024] + bhh[d + 1024];
    float go = gp[d + 1536] + bih[d + 1536] + bhh[d + 1536];
    float i = 1.f / (1.f + expf(-gi));
    float f = 1.f / (1.f + expf(-gf));
    float g = tanhf(gg);
    float o = 1.f / (1.f + expf(-go));
    float cn = f * c[idx] + i * g;
    float hn = o * tanhf(cn);
    c[idx] = cn;
    hbf[idx] = f2us(hn);
}

// ---------------------------------------------------------------------------
// K_logits_mfma: out[:,t,:](64,10000) = hbf @ WoutT(10000,512)^T + bout. grid 625.
// ---------------------------------------------------------------------------
__launch_bounds__(256)
__global__ void k_logits_mfma(int t,
                              const unsigned short* __restrict__ hbf,    // (64,512)
                              const unsigned short* __restrict__ WoutT,  // (10000,512)
                              const float* __restrict__ bout,            // (10000)
                              float* __restrict__ out)                   // (B,T,V)
{
    const int wave = threadIdx.x >> 6, lane = threadIdx.x & 63;
    const int m0 = wave * 16, n0 = blockIdx.x * 16;   // 625*16 = 10000 exact
    const int r = lane & 15, quad = lane >> 4;
    const unsigned short* ap = hbf + (size_t)(m0 + r) * ND + quad * 8;
    const unsigned short* bp = WoutT + (size_t)(n0 + r) * ND + quad * 8;
    f32x4 acc = {0.f, 0.f, 0.f, 0.f};
    #pragma unroll
    for (int k = 0; k < ND; k += 32) {
        bfrag a = *(const bfrag*)(ap + k);
        bfrag b = *(const bfrag*)(bp + k);
        acc = __builtin_amdgcn_mfma_f32_16x16x32_bf16(a, b, acc, 0, 0, 0);
    }
    const float bv = bout[n0 + r];
    #pragma unroll
    for (int i = 0; i < 4; ++i) {
        int m = m0 + quad * 4 + i;
        out[((size_t)m * NT + t) * NV + n0 + r] = acc[i] + bv;
    }
}

// ---------------------------------------------------------------------------
extern "C" void kernel_launch(void* const* d_in, const int* in_sizes, int n_in,
                              void* d_out, int out_size, void* d_ws, size_t ws_size,
                              hipStream_t stream) {
    const float* enc  = (const float*)d_in[0];
    const int*   caps = (const int*)d_in[1];
    const float* embt = (const float*)d_in[2];
    const float* Wea  = (const float*)d_in[3];
    const float* bea  = (const float*)d_in[4];
    const float* Wda  = (const float*)d_in[5];
    const float* bda  = (const float*)d_in[6];
    const float* wf   = (const float*)d_in[7];
    const float* bfs  = (const float*)d_in[8];
    const float* Wih  = (const float*)d_in[9];
    const float* bih  = (const float*)d_in[10];
    const float* Whh  = (const float*)d_in[11];
    const float* bhh  = (const float*)d_in[12];
    const float* Wh0  = (const float*)d_in[13];
    const float* bh0  = (const float*)d_in[14];
    const float* Wc0  = (const float*)d_in[15];
    const float* bc0  = (const float*)d_in[16];
    const float* Wout = (const float*)d_in[17];
    const float* bout = (const float*)d_in[18];

    float* out = (float*)d_out;                       // logits (B,T,V) f32
    float* alpha_out = out + (size_t)NB * NT * NV;    // alphas (B,T,L) f32

    // ---- workspace carve-up (16B aligned throughout) ----
    char* w = (char*)d_ws;
    float* c     = (float*)w;                 w += (size_t)NB * ND * 4;          // 128 KB
    float* dp    = (float*)w;                 w += (size_t)NB * NA * 4;          // 128 KB
    float* gates = (float*)w;                 w += (size_t)NB * 4 * ND * 4;      // 512 KB
    unsigned short* meanbf = (unsigned short*)w; w += (size_t)NB * NENC * 2;     // 256 KB
    unsigned short* hbf   = (unsigned short*)w; w += (size_t)NB * ND * 2;        // 64 KB
    unsigned short* x     = (unsigned short*)w; w += (size_t)NB * KX * 2;        // 384 KB
    unsigned short* epb   = (unsigned short*)w; w += (size_t)NB * NL * NA * 2;   // 3.2 MB
    unsigned short* encb  = (unsigned short*)w; w += (size_t)NB * NL * NENC * 2; // 12.8 MB
    unsigned short* Wihb  = (unsigned short*)w; w += (size_t)4 * ND * KIH * 2;   // 10.5 MB
    unsigned short* Whhb  = (unsigned short*)w; w += (size_t)4 * ND * ND * 2;    // 2 MB
    unsigned short* WeaT  = (unsigned short*)w; w += (size_t)NA * NENC * 2;      // 2 MB
    unsigned short* WdaT  = (unsigned short*)w; w += (size_t)NA * ND * 2;        // 0.5 MB
    unsigned short* WoutT = (unsigned short*)w; w += (size_t)NV * ND * 2;        // 10.2 MB
    unsigned short* WicT  = (unsigned short*)w; w += (size_t)2 * ND * NENC * 2;  // 4 MB

    // ---- one-time setup ----
    hipLaunchKernelGGL(k_mean, dim3(NB, NENC / 256), dim3(256), 0, stream, enc, meanbf);
    hipLaunchKernelGGL(k_transpose, dim3(ND / 32, NENC / 32), dim3(256), 0, stream,
                       Wh0, WicT, NENC, ND);
    hipLaunchKernelGGL(k_transpose, dim3(ND / 32, NENC / 32), dim3(256), 0, stream,
                       Wc0, WicT + (size_t)ND * NENC, NENC, ND);
    hipLaunchKernelGGL(k_init_mfma, dim3(2 * ND / 16), dim3(256), 0, stream,
                       meanbf, WicT, bh0, bc0, hbf, c);
    {
        int n = NB * NL * NENC;
        hipLaunchKernelGGL(k_cvt, dim3(n / 4 / 256), dim3(256), 0, stream, enc, encb, n);
    }
    {
        int n = 4 * ND * KIH;
        hipLaunchKernelGGL(k_cvt, dim3(n / 4 / 256), dim3(256), 0, stream, Wih, Wihb, n);
    }
    {
        int n = 4 * ND * ND;
        hipLaunchKernelGGL(k_cvt, dim3(n / 4 / 256), dim3(256), 0, stream, Whh, Whhb, n);
    }
    hipLaunchKernelGGL(k_transpose, dim3(NA / 32, NENC / 32), dim3(256), 0, stream,
                       Wea, WeaT, NENC, NA);
    hipLaunchKernelGGL(k_transpose, dim3(NA / 32, ND / 32), dim3(256), 0, stream,
                       Wda, WdaT, ND, NA);
    hipLaunchKernelGGL(k_transpose, dim3((NV + 31) / 32, ND / 32), dim3(256), 0, stream,
                       Wout, WoutT, ND, NV);
    hipLaunchKernelGGL(k_encproj_mfma, dim3((NB * NL / 64) * (NA / 16)), dim3(256), 0, stream,
                       encb, WeaT, bea, epb);

    // ---- 20 sequential decoder steps ----
    for (int t = 0; t < NT; ++t) {
        hipLaunchKernelGGL(k_decproj_mfma, dim3(NA / 16), dim3(256), 0, stream,
                           hbf, WdaT, bda, dp);
        hipLaunchKernelGGL(k_att, dim3(NB), dim3(256), 0, stream,
                           t, hbf, dp, epb, encb, wf, bfs, embt, caps, x, alpha_out);
        hipLaunchKernelGGL(k_gates_mfma, dim3(4 * ND / 16), dim3(256), 0, stream,
                           x, Wihb, Whhb, gates);
        hipLaunchKernelGGL(k_lstm, dim3(NB * ND / 256), dim3(256), 0, stream,
                           gates, bih, bhh, hbf, c);
        hipLaunchKernelGGL(k_logits_mfma, dim3(NV / 16), dim3(256), 0, stream,
                           t, hbf, WoutT, bout, out);
    }
}

// Round 2
// 1104.823 us; speedup vs baseline: 1.5421x; 1.4181x over previous
//
#include <hip/hip_runtime.h>
#include <hip/hip_bf16.h>

// Problem dims
constexpr int NV   = 10000;  // vocab
constexpr int NE   = 512;    // embed
constexpr int NENC = 2048;   // encoder dim
constexpr int ND   = 512;    // decoder dim
constexpr int NA   = 512;    // attention dim
constexpr int NB   = 64;     // batch
constexpr int NL   = 49;     // locations
constexpr int NT   = 20;     // steps
constexpr int KX   = NE + NENC + ND;  // 3072 : x = [emb | context | h]
constexpr int KIH  = NE + NENC;       // 2560 : W_ih inner dim

typedef short bfrag __attribute__((ext_vector_type(8)));   // 8 bf16 (4 VGPRs)
typedef float f32x4 __attribute__((ext_vector_type(4)));   // MFMA acc

__device__ __forceinline__ float us2f(unsigned short u) {
    union { unsigned int i; float f; } x; x.i = (unsigned int)u << 16; return x.f;
}
__device__ __forceinline__ unsigned short f2us(float f) {  // RNE f32->bf16
    union { float f_; unsigned int u; } x; x.f_ = f;
    unsigned int r = (x.u + 0x7fffu + ((x.u >> 16) & 1u)) >> 16;
    return (unsigned short)r;
}

// ---------------------------------------------------------------------------
// K_mean: mean over L -> bf16. grid (B, NENC/256). Coalesced.
// ---------------------------------------------------------------------------
__launch_bounds__(256)
__global__ void k_mean(const float* __restrict__ enc, unsigned short* __restrict__ meanbf)
{
    const int b = blockIdx.x;
    const int e = blockIdx.y * 256 + threadIdx.x;
    const float* p = enc + (size_t)b * NL * NENC + e;
    float s = 0.f;
    #pragma unroll 7
    for (int l = 0; l < NL; ++l) s += p[(size_t)l * NENC];
    meanbf[(size_t)b * NENC + e] = f2us(s * (1.0f / NL));
}

// ---------------------------------------------------------------------------
// K_init_mfma: [h|c](64,1024) = meanbf(64,2048) @ WicT(1024,2048)^T + bias.
// ---------------------------------------------------------------------------
__launch_bounds__(256)
__global__ void k_init_mfma(const unsigned short* __restrict__ meanbf,  // (64,2048)
                            const unsigned short* __restrict__ WicT,    // (1024,2048)
                            const float* __restrict__ bh, const float* __restrict__ bc,
                            unsigned short* __restrict__ hbf, float* __restrict__ c)
{
    const int wave = threadIdx.x >> 6, lane = threadIdx.x & 63;
    const int m0 = wave * 16, n0 = blockIdx.x * 16;   // 64*16 = 1024 cols
    const int r = lane & 15, quad = lane >> 4;
    const unsigned short* ap = meanbf + (size_t)(m0 + r) * NENC + quad * 8;
    const unsigned short* bp = WicT   + (size_t)(n0 + r) * NENC + quad * 8;
    f32x4 acc = {0.f, 0.f, 0.f, 0.f};
    #pragma unroll 8
    for (int k = 0; k < NENC; k += 32) {
        bfrag a = *(const bfrag*)(ap + k);
        bfrag b = *(const bfrag*)(bp + k);
        acc = __builtin_amdgcn_mfma_f32_16x16x32_bf16(a, b, acc, 0, 0, 0);
    }
    const int n = n0 + r;
    const bool isC = n >= ND;
    const float bv = isC ? bc[n - ND] : bh[n];
    #pragma unroll
    for (int i = 0; i < 4; ++i) {
        int m = m0 + quad * 4 + i;
        float v = acc[i] + bv;
        if (isC) c[(size_t)m * ND + (n - ND)] = v;
        else     hbf[(size_t)m * ND + n] = f2us(v);
    }
}

// ---------------------------------------------------------------------------
// K_cvt: f32 -> bf16 flat copy (n multiple of 4).
// ---------------------------------------------------------------------------
__launch_bounds__(256)
__global__ void k_cvt(const float* __restrict__ src, unsigned short* __restrict__ dst, int n)
{
    int i = (blockIdx.x * 256 + threadIdx.x) * 4;
    if (i < n) {
        float4 v = *(const float4*)(src + i);
        dst[i + 0] = f2us(v.x); dst[i + 1] = f2us(v.y);
        dst[i + 2] = f2us(v.z); dst[i + 3] = f2us(v.w);
    }
}

// ---------------------------------------------------------------------------
// K_transpose: (K,N) f32 -> (N,K) bf16.  grid (ceil(N/32), K/32), 256 thr.
// ---------------------------------------------------------------------------
__launch_bounds__(256)
__global__ void k_transpose(const float* __restrict__ src, unsigned short* __restrict__ dst,
                            int K, int N)
{
    __shared__ float t[32][33];
    const int nb = blockIdx.x * 32, kb = blockIdx.y * 32;
    const int tx = threadIdx.x & 31, ty = threadIdx.x >> 5;  // ty 0..7
    #pragma unroll
    for (int i = ty; i < 32; i += 8) {
        int n = nb + tx;
        t[i][tx] = (n < N) ? src[(size_t)(kb + i) * N + n] : 0.f;
    }
    __syncthreads();
    #pragma unroll
    for (int i = ty; i < 32; i += 8) {
        int n = nb + i;
        if (n < N) dst[(size_t)n * K + kb + tx] = f2us(t[tx][i]);
    }
}

// ---------------------------------------------------------------------------
// K_encproj_mfma: epb(3136,512)bf16 = encb(3136,2048) @ WeaT(512,2048)^T + bias
// wave = 32x32 out (2x2 tiles, 1.0 load/MFMA); block = 64x64; grid 49*8.
// n fastest in bid so bid%8 = n-group -> B-panel pinned per XCD.
// ---------------------------------------------------------------------------
__launch_bounds__(256)
__global__ void k_encproj_mfma(const unsigned short* __restrict__ encb,
                               const unsigned short* __restrict__ WeaT,
                               const float* __restrict__ bias,
                               unsigned short* __restrict__ epb)
{
    const int wave = threadIdx.x >> 6, lane = threadIdx.x & 63;
    const int ng = blockIdx.x & 7;                 // 0..7  (n-group, 64 cols)
    const int mg = blockIdx.x >> 3;                // 0..48 (m-group, 64 rows)
    const int wm = wave >> 1, wn = wave & 1;
    const int m0 = mg * 64 + wm * 32;
    const int n0 = ng * 64 + wn * 32;
    const int r = lane & 15, quad = lane >> 4;
    const unsigned short* ap0 = encb + (size_t)(m0 + r) * NENC + quad * 8;
    const unsigned short* ap1 = ap0 + (size_t)16 * NENC;
    const unsigned short* bp0 = WeaT + (size_t)(n0 + r) * NENC + quad * 8;
    const unsigned short* bp1 = bp0 + (size_t)16 * NENC;
    f32x4 acc00 = {0.f,0.f,0.f,0.f}, acc01 = {0.f,0.f,0.f,0.f};
    f32x4 acc10 = {0.f,0.f,0.f,0.f}, acc11 = {0.f,0.f,0.f,0.f};
    #pragma unroll 4
    for (int k = 0; k < NENC; k += 32) {
        bfrag a0 = *(const bfrag*)(ap0 + k);
        bfrag a1 = *(const bfrag*)(ap1 + k);
        bfrag b0 = *(const bfrag*)(bp0 + k);
        bfrag b1 = *(const bfrag*)(bp1 + k);
        acc00 = __builtin_amdgcn_mfma_f32_16x16x32_bf16(a0, b0, acc00, 0, 0, 0);
        acc01 = __builtin_amdgcn_mfma_f32_16x16x32_bf16(a0, b1, acc01, 0, 0, 0);
        acc10 = __builtin_amdgcn_mfma_f32_16x16x32_bf16(a1, b0, acc10, 0, 0, 0);
        acc11 = __builtin_amdgcn_mfma_f32_16x16x32_bf16(a1, b1, acc11, 0, 0, 0);
    }
    const float bv0 = bias[n0 + r], bv1 = bias[n0 + 16 + r];
    #pragma unroll
    for (int i = 0; i < 4; ++i) {
        int ma = m0 + quad * 4 + i, mb = ma + 16;
        epb[(size_t)ma * NA + n0 + r]      = f2us(acc00[i] + bv0);
        epb[(size_t)ma * NA + n0 + 16 + r] = f2us(acc01[i] + bv1);
        epb[(size_t)mb * NA + n0 + r]      = f2us(acc10[i] + bv0);
        epb[(size_t)mb * NA + n0 + 16 + r] = f2us(acc11[i] + bv1);
    }
}

// ---------------------------------------------------------------------------
// K_att: one block (512 thr) per b. scores=relu(ep+dp)@wf+b -> softmax ->
// alpha; context from encb -> x middle; x=[emb|context|h].
// ---------------------------------------------------------------------------
__launch_bounds__(512)
__global__ void k_att(int t,
                      const unsigned short* __restrict__ hbf,   // (B,D) bf16
                      const float* __restrict__ dpg,            // (B,A) f32
                      const unsigned short* __restrict__ epb,   // (B,L,A) bf16
                      const unsigned short* __restrict__ encb,  // (B,L,ENC) bf16
                      const float* __restrict__ wf,             // (A)
                      const float* __restrict__ bfs,            // scalar
                      const float* __restrict__ embt,           // (V,E) f32
                      const int* __restrict__ captions,         // (B,T)
                      unsigned short* __restrict__ x,           // (B,KX) bf16
                      float* __restrict__ alpha_out)            // (B,T,L) f32
{
    __shared__ float dp[NA];
    __shared__ float al[64];
    const int b = blockIdx.x, tid = threadIdx.x;

    for (int d = tid; d < ND; d += 512)
        x[(size_t)b * KX + NE + NENC + d] = hbf[(size_t)b * ND + d];  // h tail
    for (int a = tid; a < NA; a += 512)
        dp[a] = dpg[(size_t)b * NA + a];
    const int tok = captions[b * NT + t];
    for (int j = tid; j < NE; j += 512)
        x[(size_t)b * KX + j] = f2us(embt[(size_t)tok * NE + j]);
    __syncthreads();

    // scores: one wave per l
    const int wave = tid >> 6, lane = tid & 63;
    const float bfull = bfs[0];
    for (int l = wave; l < NL; l += 8) {
        const unsigned short* ep = epb + ((size_t)b * NL + l) * NA;
        float s = 0.f;
        #pragma unroll
        for (int a = lane; a < NA; a += 64) {
            float v = us2f(ep[a]) + dp[a];
            v = v > 0.f ? v : 0.f;
            s = fmaf(v, wf[a], s);
        }
        #pragma unroll
        for (int off = 32; off > 0; off >>= 1) s += __shfl_down(s, off, 64);
        if (lane == 0) al[l] = s + bfull;
    }
    __syncthreads();

    // softmax over L=49 (first wave)
    if (tid < 64) {
        float v = (tid < NL) ? al[tid] : -1e30f;
        float m = v;
        #pragma unroll
        for (int off = 32; off > 0; off >>= 1) m = fmaxf(m, __shfl_xor(m, off, 64));
        float e = (tid < NL) ? expf(v - m) : 0.f;
        float s = e;
        #pragma unroll
        for (int off = 32; off > 0; off >>= 1) s += __shfl_xor(s, off, 64);
        float a = e / s;
        if (tid < NL) {
            al[tid] = a;
            alpha_out[((size_t)b * NT + t) * NL + tid] = a;
        }
    }
    __syncthreads();

    // context -> x middle, bf16. thread covers 4 consecutive e, one pass.
    {
        const int e = tid * 4;
        const unsigned short* p = encb + (size_t)b * NL * NENC + e;
        float s0 = 0.f, s1 = 0.f, s2 = 0.f, s3 = 0.f;
        #pragma unroll 7
        for (int l = 0; l < NL; ++l) {
            ushort4 v = *(const ushort4*)(p + (size_t)l * NENC);
            float a = al[l];
            s0 = fmaf(a, us2f(v.x), s0);
            s1 = fmaf(a, us2f(v.y), s1);
            s2 = fmaf(a, us2f(v.z), s2);
            s3 = fmaf(a, us2f(v.w), s3);
        }
        unsigned short* xo = x + (size_t)b * KX + NE + e;
        xo[0] = f2us(s0); xo[1] = f2us(s1); xo[2] = f2us(s2); xo[3] = f2us(s3);
    }
}

// ---------------------------------------------------------------------------
// K_gates_lstm: fused gates GEMM + LSTM pointwise.
// grid 128 = (n-group ng 0..31) x (m-tile mt 0..3); 256 thr = 4 waves K-split.
// Block computes gates for all 4 gate sections at cols [ng*16,ng*16+16),
// rows [mt*16, mt*16+16). Wave w covers K chunk [w*768,(w+1)*768).
// LDS combine, then wave 0 does the lane-local LSTM epilogue:
// acc[g][i] for g=0..3 all live at the same (m,d).
// ---------------------------------------------------------------------------
__launch_bounds__(256)
__global__ void k_gates_lstm(const unsigned short* __restrict__ x,     // (64,3072)
                             const unsigned short* __restrict__ Wihb,  // (2048,2560)
                             const unsigned short* __restrict__ Whhb,  // (2048,512)
                             const float* __restrict__ bih, const float* __restrict__ bhh,
                             unsigned short* __restrict__ hbf, float* __restrict__ c)
{
    __shared__ float part[3][4][16][16];   // 12 KB
    const int wave = threadIdx.x >> 6, lane = threadIdx.x & 63;
    const int ng = blockIdx.x & 31, mt = blockIdx.x >> 5;
    const int m0 = mt * 16, n0 = ng * 16;
    const int r = lane & 15, quad = lane >> 4;
    const int k0 = wave * (KX / 4);        // 0,768,1536,2304
    const int k1 = k0 + (KX / 4);

    const unsigned short* ap = x + (size_t)(m0 + r) * KX + quad * 8;
    f32x4 acc[4] = {{0.f,0.f,0.f,0.f},{0.f,0.f,0.f,0.f},
                    {0.f,0.f,0.f,0.f},{0.f,0.f,0.f,0.f}};

    // part 1: K in Wihb range [k0, min(k1,KIH))
    const int kiA = (k1 < KIH) ? k1 : KIH;
    #pragma unroll 4
    for (int k = k0; k < kiA; k += 32) {
        bfrag a = *(const bfrag*)(ap + k);
        #pragma unroll
        for (int g = 0; g < 4; ++g) {
            const unsigned short* bp = Wihb + (size_t)(g * ND + n0 + r) * KIH + quad * 8;
            bfrag b = *(const bfrag*)(bp + k);
            acc[g] = __builtin_amdgcn_mfma_f32_16x16x32_bf16(a, b, acc[g], 0, 0, 0);
        }
    }
    // part 2: K in Whhb range [max(k0,KIH), k1)
    const int kiB = (k0 > KIH) ? k0 : KIH;
    #pragma unroll 4
    for (int k = kiB; k < k1; k += 32) {
        bfrag a = *(const bfrag*)(ap + k);
        #pragma unroll
        for (int g = 0; g < 4; ++g) {
            const unsigned short* bp = Whhb + (size_t)(g * ND + n0 + r) * ND + quad * 8;
            bfrag b = *(const bfrag*)(bp + (k - KIH));
            acc[g] = __builtin_amdgcn_mfma_f32_16x16x32_bf16(a, b, acc[g], 0, 0, 0);
        }
    }

    if (wave > 0) {
        #pragma unroll
        for (int g = 0; g < 4; ++g)
            #pragma unroll
            for (int i = 0; i < 4; ++i)
                part[wave - 1][g][quad * 4 + i][r] = acc[g][i];
    }
    __syncthreads();
    if (wave == 0) {
        #pragma unroll
        for (int g = 0; g < 4; ++g)
            #pragma unroll
            for (int i = 0; i < 4; ++i)
                acc[g][i] += part[0][g][quad * 4 + i][r]
                           + part[1][g][quad * 4 + i][r]
                           + part[2][g][quad * 4 + i][r];
        const int d = n0 + r;
        const float b0 = bih[d]        + bhh[d];
        const float b1 = bih[d + 512]  + bhh[d + 512];
        const float b2 = bih[d + 1024] + bhh[d + 1024];
        const float b3 = bih[d + 1536] + bhh[d + 1536];
        #pragma unroll
        for (int i = 0; i < 4; ++i) {
            const int m = m0 + quad * 4 + i;
            float gi = acc[0][i] + b0;
            float gf = acc[1][i] + b1;
            float gg = acc[2][i] + b2;
            float go = acc[3][i] + b3;
            float ig = 1.f / (1.f + expf(-gi));
            float fg = 1.f / (1.f + expf(-gf));
            float g  = tanhf(gg);
            float og = 1.f / (1.f + expf(-go));
            float cn = fg * c[(size_t)m * ND + d] + ig * g;
            float hn = og * tanhf(cn);
            c[(size_t)m * ND + d] = cn;
            hbf[(size_t)m * ND + d] = f2us(hn);
        }
    }
}

// ---------------------------------------------------------------------------
// K_logits_decproj: fused — blocks [0,nlog) do logits tiles for step t;
// blocks [nlog, nlog+32) do dp = hbf @ WdaT^T + bda (for step t+1).
// Pre-loop: nlog=0, grid 32 -> decproj only (dp(0) from h_init).
// ---------------------------------------------------------------------------
__launch_bounds__(256)
__global__ void k_logits_decproj(int t, int nlog,
                                 const unsigned short* __restrict__ hbf,    // (64,512)
                                 const unsigned short* __restrict__ WoutT,  // (10000,512)
                                 const float* __restrict__ bout,            // (10000)
                                 float* __restrict__ out,                   // (B,T,V)
                                 const unsigned short* __restrict__ WdaT,   // (512,512)
                                 const float* __restrict__ bda,             // (512)
                                 float* __restrict__ dp)                    // (64,512)
{
    const int wave = threadIdx.x >> 6, lane = threadIdx.x & 63;
    const int r = lane & 15, quad = lane >> 4;
    const int m0 = wave * 16;
    if ((int)blockIdx.x < nlog) {
        const int n0 = blockIdx.x * 16;   // 625*16 = 10000 exact
        const unsigned short* ap = hbf + (size_t)(m0 + r) * ND + quad * 8;
        const unsigned short* bp = WoutT + (size_t)(n0 + r) * ND + quad * 8;
        f32x4 acc = {0.f, 0.f, 0.f, 0.f};
        #pragma unroll
        for (int k = 0; k < ND; k += 32) {
            bfrag a = *(const bfrag*)(ap + k);
            bfrag b = *(const bfrag*)(bp + k);
            acc = __builtin_amdgcn_mfma_f32_16x16x32_bf16(a, b, acc, 0, 0, 0);
        }
        const float bv = bout[n0 + r];
        #pragma unroll
        for (int i = 0; i < 4; ++i) {
            int m = m0 + quad * 4 + i;
            out[((size_t)m * NT + t) * NV + n0 + r] = acc[i] + bv;
        }
    } else {
        const int n0 = ((int)blockIdx.x - nlog) * 16;
        const unsigned short* ap = hbf + (size_t)(m0 + r) * ND + quad * 8;
        const unsigned short* bp = WdaT + (size_t)(n0 + r) * ND + quad * 8;
        f32x4 acc = {0.f, 0.f, 0.f, 0.f};
        #pragma unroll
        for (int k = 0; k < ND; k += 32) {
            bfrag a = *(const bfrag*)(ap + k);
            bfrag b = *(const bfrag*)(bp + k);
            acc = __builtin_amdgcn_mfma_f32_16x16x32_bf16(a, b, acc, 0, 0, 0);
        }
        const float bv = bda[n0 + r];
        #pragma unroll
        for (int i = 0; i < 4; ++i) {
            int m = m0 + quad * 4 + i;
            dp[(size_t)m * NA + n0 + r] = acc[i] + bv;
        }
    }
}

// ---------------------------------------------------------------------------
extern "C" void kernel_launch(void* const* d_in, const int* in_sizes, int n_in,
                              void* d_out, int out_size, void* d_ws, size_t ws_size,
                              hipStream_t stream) {
    const float* enc  = (const float*)d_in[0];
    const int*   caps = (const int*)d_in[1];
    const float* embt = (const float*)d_in[2];
    const float* Wea  = (const float*)d_in[3];
    const float* bea  = (const float*)d_in[4];
    const float* Wda  = (const float*)d_in[5];
    const float* bda  = (const float*)d_in[6];
    const float* wf   = (const float*)d_in[7];
    const float* bfs  = (const float*)d_in[8];
    const float* Wih  = (const float*)d_in[9];
    const float* bih  = (const float*)d_in[10];
    const float* Whh  = (const float*)d_in[11];
    const float* bhh  = (const float*)d_in[12];
    const float* Wh0  = (const float*)d_in[13];
    const float* bh0  = (const float*)d_in[14];
    const float* Wc0  = (const float*)d_in[15];
    const float* bc0  = (const float*)d_in[16];
    const float* Wout = (const float*)d_in[17];
    const float* bout = (const float*)d_in[18];

    float* out = (float*)d_out;                       // logits (B,T,V) f32
    float* alpha_out = out + (size_t)NB * NT * NV;    // alphas (B,T,L) f32

    // ---- workspace carve-up (16B aligned throughout) ----
    char* w = (char*)d_ws;
    float* c     = (float*)w;                 w += (size_t)NB * ND * 4;          // 128 KB
    float* dp    = (float*)w;                 w += (size_t)NB * NA * 4;          // 128 KB
    unsigned short* meanbf = (unsigned short*)w; w += (size_t)NB * NENC * 2;     // 256 KB
    unsigned short* hbf   = (unsigned short*)w; w += (size_t)NB * ND * 2;        // 64 KB
    unsigned short* x     = (unsigned short*)w; w += (size_t)NB * KX * 2;        // 384 KB
    unsigned short* epb   = (unsigned short*)w; w += (size_t)NB * NL * NA * 2;   // 3.2 MB
    unsigned short* encb  = (unsigned short*)w; w += (size_t)NB * NL * NENC * 2; // 12.8 MB
    unsigned short* Wihb  = (unsigned short*)w; w += (size_t)4 * ND * KIH * 2;   // 10.5 MB
    unsigned short* Whhb  = (unsigned short*)w; w += (size_t)4 * ND * ND * 2;    // 2 MB
    unsigned short* WeaT  = (unsigned short*)w; w += (size_t)NA * NENC * 2;      // 2 MB
    unsigned short* WdaT  = (unsigned short*)w; w += (size_t)NA * ND * 2;        // 0.5 MB
    unsigned short* WoutT = (unsigned short*)w; w += (size_t)NV * ND * 2;        // 10.2 MB
    unsigned short* WicT  = (unsigned short*)w; w += (size_t)2 * ND * NENC * 2;  // 4 MB

    // ---- one-time setup ----
    hipLaunchKernelGGL(k_mean, dim3(NB, NENC / 256), dim3(256), 0, stream, enc, meanbf);
    hipLaunchKernelGGL(k_transpose, dim3(ND / 32, NENC / 32), dim3(256), 0, stream,
                       Wh0, WicT, NENC, ND);
    hipLaunchKernelGGL(k_transpose, dim3(ND / 32, NENC / 32), dim3(256), 0, stream,
                       Wc0, WicT + (size_t)ND * NENC, NENC, ND);
    hipLaunchKernelGGL(k_init_mfma, dim3(2 * ND / 16), dim3(256), 0, stream,
                       meanbf, WicT, bh0, bc0, hbf, c);
    {
        int n = NB * NL * NENC;
        hipLaunchKernelGGL(k_cvt, dim3(n / 4 / 256), dim3(256), 0, stream, enc, encb, n);
    }
    {
        int n = 4 * ND * KIH;
        hipLaunchKernelGGL(k_cvt, dim3(n / 4 / 256), dim3(256), 0, stream, Wih, Wihb, n);
    }
    {
        int n = 4 * ND * ND;
        hipLaunchKernelGGL(k_cvt, dim3(n / 4 / 256), dim3(256), 0, stream, Whh, Whhb, n);
    }
    hipLaunchKernelGGL(k_transpose, dim3(NA / 32, NENC / 32), dim3(256), 0, stream,
                       Wea, WeaT, NENC, NA);
    hipLaunchKernelGGL(k_transpose, dim3(NA / 32, ND / 32), dim3(256), 0, stream,
                       Wda, WdaT, ND, NA);
    hipLaunchKernelGGL(k_transpose, dim3((NV + 31) / 32, ND / 32), dim3(256), 0, stream,
                       Wout, WoutT, ND, NV);
    hipLaunchKernelGGL(k_encproj_mfma, dim3((NB * NL / 64) * (NA / 64)), dim3(256), 0, stream,
                       encb, WeaT, bea, epb);
    // dp(0) from h_init (decproj only)
    hipLaunchKernelGGL(k_logits_decproj, dim3(32), dim3(256), 0, stream,
                       0, 0, hbf, WoutT, bout, out, WdaT, bda, dp);

    // ---- 20 sequential decoder steps, 3 dispatches each ----
    for (int t = 0; t < NT; ++t) {
        hipLaunchKernelGGL(k_att, dim3(NB), dim3(512), 0, stream,
                           t, hbf, dp, epb, encb, wf, bfs, embt, caps, x, alpha_out);
        hipLaunchKernelGGL(k_gates_lstm, dim3(128), dim3(256), 0, stream,
                           x, Wihb, Whhb, bih, bhh, hbf, c);
        hipLaunchKernelGGL(k_logits_decproj, dim3(NV / 16 + 32), dim3(256), 0, stream,
                           t, NV / 16, hbf, WoutT, bout, out, WdaT, bda, dp);
    }
}